// Round 1
// baseline (113.084 us; speedup 1.0000x reference)
//
#include <hip/hip_runtime.h>
#include <hip/hip_bf16.h>

// GAT layer, B=4, N=4096, F_in=128, F_out=64.
// out_i = sum_j adj_ij * exp(leaky(s2_i+s1_j)) * Wh_j
//         / ( sum_j adj_ij*exp(..) + 1e-9 * sum_j exp(..) )
// (softmax max-subtraction cancels exactly; e <= ~6 so exp() is safe bare)

typedef __attribute__((ext_vector_type(8))) short bf16x8;
typedef __attribute__((ext_vector_type(4))) float f32x4;

#define LOG2E 1.4426950408889634f

__device__ __forceinline__ unsigned short f2bf(float x) {
  union { float f; unsigned int u; } c; c.f = x;
  unsigned int r = c.u + 0x7fffu + ((c.u >> 16) & 1u);  // RNE
  return (unsigned short)(r >> 16);
}
__device__ __forceinline__ float bf2f(unsigned short s) {
  union { unsigned int u; float f; } c; c.u = ((unsigned int)s) << 16; return c.f;
}

// ---------------- K1: Wh = h @ W (f32), store WhT as bf16 hi/lo [b][64][4096]
__global__ __launch_bounds__(256) void k_wh(
    const float* __restrict__ h, const float* __restrict__ W,
    unsigned short* __restrict__ wtHi, unsigned short* __restrict__ wtLo) {
  __shared__ float hs[32][130];   // h tile, pad 130 for bank spread
  const int t = threadIdx.x;
  const int b = blockIdx.x >> 7;
  const int row0 = (blockIdx.x & 127) << 5;   // 32-row tiles

  // stage h tile: 32 rows x 128 f32
  #pragma unroll
  for (int it = 0; it < 4; ++it) {
    int flat = it * 256 + t;
    int r = flat >> 5, q = flat & 31;
    const float4 v = *(const float4*)(h + ((size_t)(b * 4096 + row0 + r)) * 128 + 4 * q);
    hs[r][4*q+0] = v.x; hs[r][4*q+1] = v.y; hs[r][4*q+2] = v.z; hs[r][4*q+3] = v.w;
  }
  __syncthreads();

  const int rg = t >> 4, cg = t & 15;   // thread: rows 2rg..2rg+1, cols 4cg..4cg+3
  float acc[2][4] = {};
  for (int k = 0; k < 128; ++k) {
    float4 wv = *(const float4*)(W + k * 64 + 4 * cg);  // W from L1/L2 (32KB, hot)
    #pragma unroll
    for (int i = 0; i < 2; ++i) {
      float hv = hs[2*rg + i][k];
      acc[i][0] = fmaf(hv, wv.x, acc[i][0]);
      acc[i][1] = fmaf(hv, wv.y, acc[i][1]);
      acc[i][2] = fmaf(hv, wv.z, acc[i][2]);
      acc[i][3] = fmaf(hv, wv.w, acc[i][3]);
    }
  }
  __syncthreads();

  // transpose via LDS (reuse hs region), then coalesced bf16 hi/lo stores
  float (*WhF)[68] = (float(*)[68])hs;   // 32 x 68 f32 fits in hs region
  #pragma unroll
  for (int i = 0; i < 2; ++i)
    #pragma unroll
    for (int j = 0; j < 4; ++j)
      WhF[2*rg + i][4*cg + j] = acc[i][j];
  __syncthreads();

  const int col = t >> 2, sub = t & 3;   // thread: one col, 8 rows
  unsigned short hi[8], lo[8];
  #pragma unroll
  for (int r = 0; r < 8; ++r) {
    float v = WhF[8*sub + r][col];
    unsigned short hb = f2bf(v);
    hi[r] = hb;
    lo[r] = f2bf(v - bf2f(hb));   // residual: Wh ~= hi + lo to ~2^-18
  }
  unsigned int uh[4], ul[4];
  #pragma unroll
  for (int r = 0; r < 4; ++r) {
    uh[r] = (unsigned)hi[2*r] | ((unsigned)hi[2*r+1] << 16);
    ul[r] = (unsigned)lo[2*r] | ((unsigned)lo[2*r+1] << 16);
  }
  size_t base = ((size_t)(b * 64 + col)) * 4096 + row0 + 8 * sub;
  *(uint4*)(wtHi + base) = make_uint4(uh[0], uh[1], uh[2], uh[3]);
  *(uint4*)(wtLo + base) = make_uint4(ul[0], ul[1], ul[2], ul[3]);
}

// ---------------- K2: s1 = h @ (W a1), s2 = h @ (W a2)
__global__ __launch_bounds__(256) void k_s12(
    const float* __restrict__ h, const float* __restrict__ W, const float* __restrict__ a,
    float* __restrict__ s1, float* __restrict__ s2) {
  __shared__ float wa1[128], wa2[128];
  const int t = threadIdx.x;
  if (t < 128) {
    float x1 = 0.f, x2 = 0.f;
    for (int o = 0; o < 64; ++o) {
      float w = W[t * 64 + o];
      x1 = fmaf(w, a[o], x1);
      x2 = fmaf(w, a[64 + o], x2);
    }
    wa1[t] = x1; wa2[t] = x2;
  }
  __syncthreads();
  const int row = blockIdx.x * 256 + t;   // 0..16383
  const float* hr = h + (size_t)row * 128;
  float x1 = 0.f, x2 = 0.f;
  #pragma unroll 8
  for (int q = 0; q < 32; ++q) {
    float4 v = *(const float4*)(hr + 4 * q);
    x1 = fmaf(v.x, wa1[4*q+0], x1); x1 = fmaf(v.y, wa1[4*q+1], x1);
    x1 = fmaf(v.z, wa1[4*q+2], x1); x1 = fmaf(v.w, wa1[4*q+3], x1);
    x2 = fmaf(v.x, wa2[4*q+0], x2); x2 = fmaf(v.y, wa2[4*q+1], x2);
    x2 = fmaf(v.z, wa2[4*q+2], x2); x2 = fmaf(v.w, wa2[4*q+3], x2);
  }
  s1[row] = x1; s2[row] = x2;
}

// ---------------- K3: fused  out = P @ (WhHi + WhLo), P built on the fly
// block: 32 output rows x 64 cols, 256 threads (4 waves: 2x2 of 16x32 tiles)
__global__ __launch_bounds__(256) void k_main(
    const float* __restrict__ adj,
    const unsigned short* __restrict__ wtHi, const unsigned short* __restrict__ wtLo,
    const float* __restrict__ s1, const float* __restrict__ s2,
    float* __restrict__ out) {
  __shared__ unsigned short Pw[32 * 72];    // P tile, rows padded to 72 bf16
  __shared__ unsigned short BhS[64 * 72];   // WhT hi tile [col][k]
  __shared__ unsigned short BlS[64 * 72];   // WhT lo tile
  __shared__ float Zs[32], Ss[32];

  const int t = threadIdx.x;
  const int b = blockIdx.x >> 7;
  const int row0 = (blockIdx.x & 127) << 5;
  const int lane = t & 63, w = t >> 6;
  const int jj = t & 15, prow = t >> 4;       // P-staging role
  const int scol = t >> 2, sq = t & 3;        // WhT-staging role
  const int g = lane >> 4, lr = lane & 15;    // mfma fragment role
  const int rh = w >> 1, ch = w & 1;          // wave -> (row half, col half)

  const float* adjR0 = adj + ((size_t)(b * 4096 + row0) + prow) * 4096;
  const float* adjR1 = adjR0 + (size_t)16 * 4096;
  const float s2v0 = s2[b * 4096 + row0 + prow];
  const float s2v1 = s2[b * 4096 + row0 + 16 + prow];
  const unsigned short* gh = wtHi + ((size_t)(b * 64 + scol)) * 4096 + 8 * sq;
  const unsigned short* gl = wtLo + ((size_t)(b * 64 + scol)) * 4096 + 8 * sq;
  const float* s1b = s1 + b * 4096 + 4 * jj;

  float z0 = 0.f, z1 = 0.f, sa0 = 0.f, sa1 = 0.f;
  f32x4 acc0 = {0.f, 0.f, 0.f, 0.f}, acc1 = {0.f, 0.f, 0.f, 0.f};

  for (int k0 = 0; k0 < 4096; k0 += 64) {
    // global loads for this K-step (issued up front)
    const float4 av0 = *(const float4*)(adjR0 + k0 + 4 * jj);
    const float4 av1 = *(const float4*)(adjR1 + k0 + 4 * jj);
    const float4 s1v = *(const float4*)(s1b + k0);
    const uint4 th0 = *(const uint4*)(gh + k0);
    const uint4 th1 = *(const uint4*)(gh + k0 + 32);
    const uint4 tl0 = *(const uint4*)(gl + k0);
    const uint4 tl1 = *(const uint4*)(gl + k0 + 32);

    // P pass 0: row = prow
    {
      float e0 = s2v0 + s1v.x, e1 = s2v0 + s1v.y, e2 = s2v0 + s1v.z, e3 = s2v0 + s1v.w;
      e0 = fmaxf(e0, 0.2f * e0); e1 = fmaxf(e1, 0.2f * e1);
      e2 = fmaxf(e2, 0.2f * e2); e3 = fmaxf(e3, 0.2f * e3);
      float p0 = exp2f(e0 * LOG2E), p1 = exp2f(e1 * LOG2E);
      float p2 = exp2f(e2 * LOG2E), p3 = exp2f(e3 * LOG2E);
      float w0 = av0.x * p0, w1 = av0.y * p1, w2 = av0.z * p2, w3 = av0.w * p3;
      z0 += (p0 + p1) + (p2 + p3);
      sa0 += (w0 + w1) + (w2 + w3);
      ushort4 pk; pk.x = f2bf(w0); pk.y = f2bf(w1); pk.z = f2bf(w2); pk.w = f2bf(w3);
      *(ushort4*)&Pw[prow * 72 + 4 * jj] = pk;
    }
    // P pass 1: row = 16 + prow
    {
      float e0 = s2v1 + s1v.x, e1 = s2v1 + s1v.y, e2 = s2v1 + s1v.z, e3 = s2v1 + s1v.w;
      e0 = fmaxf(e0, 0.2f * e0); e1 = fmaxf(e1, 0.2f * e1);
      e2 = fmaxf(e2, 0.2f * e2); e3 = fmaxf(e3, 0.2f * e3);
      float p0 = exp2f(e0 * LOG2E), p1 = exp2f(e1 * LOG2E);
      float p2 = exp2f(e2 * LOG2E), p3 = exp2f(e3 * LOG2E);
      float w0 = av1.x * p0, w1 = av1.y * p1, w2 = av1.z * p2, w3 = av1.w * p3;
      z1 += (p0 + p1) + (p2 + p3);
      sa1 += (w0 + w1) + (w2 + w3);
      ushort4 pk; pk.x = f2bf(w0); pk.y = f2bf(w1); pk.z = f2bf(w2); pk.w = f2bf(w3);
      *(ushort4*)&Pw[(16 + prow) * 72 + 4 * jj] = pk;
    }
    // stage WhT hi/lo tiles [64 cols][64 k]
    *(uint4*)&BhS[scol * 72 + 8 * sq] = th0;
    *(uint4*)&BhS[scol * 72 + 32 + 8 * sq] = th1;
    *(uint4*)&BlS[scol * 72 + 8 * sq] = tl0;
    *(uint4*)&BlS[scol * 72 + 32 + 8 * sq] = tl1;
    __syncthreads();

    // MFMA: A = P rows [16rh..16rh+16), B = cols [32ch..32ch+32)
    #pragma unroll
    for (int kk = 0; kk < 2; ++kk) {
      const bf16x8 af = *(const bf16x8*)&Pw[(16 * rh + lr) * 72 + kk * 32 + 8 * g];
      const int c0 = (32 * ch + lr) * 72 + kk * 32 + 8 * g;
      const bf16x8 bh0 = *(const bf16x8*)&BhS[c0];
      const bf16x8 bl0 = *(const bf16x8*)&BlS[c0];
      const bf16x8 bh1 = *(const bf16x8*)&BhS[c0 + 16 * 72];
      const bf16x8 bl1 = *(const bf16x8*)&BlS[c0 + 16 * 72];
      acc0 = __builtin_amdgcn_mfma_f32_16x16x32_bf16(af, bh0, acc0, 0, 0, 0);
      acc0 = __builtin_amdgcn_mfma_f32_16x16x32_bf16(af, bl0, acc0, 0, 0, 0);
      acc1 = __builtin_amdgcn_mfma_f32_16x16x32_bf16(af, bh1, acc1, 0, 0, 0);
      acc1 = __builtin_amdgcn_mfma_f32_16x16x32_bf16(af, bl1, acc1, 0, 0, 0);
    }
    __syncthreads();
  }

  // reduce Z/S across the 16 lanes sharing a row
  #pragma unroll
  for (int m = 1; m < 16; m <<= 1) {
    z0 += __shfl_xor(z0, m);  z1 += __shfl_xor(z1, m);
    sa0 += __shfl_xor(sa0, m); sa1 += __shfl_xor(sa1, m);
  }
  if (jj == 0) {
    Zs[prow] = z0;      Ss[prow] = sa0;
    Zs[16 + prow] = z1; Ss[16 + prow] = sa1;
  }
  __syncthreads();

  // epilogue: scale by 1/(S + eps*Z), write f32 out
  #pragma unroll
  for (int reg = 0; reg < 4; ++reg) {
    int rl = 16 * rh + 4 * g + reg;
    float inv = 1.0f / (Ss[rl] + 1e-9f * Zs[rl]);
    size_t ob = ((size_t)(b * 4096 + row0 + rl)) * 64 + 32 * ch + lr;
    out[ob] = acc0[reg] * inv;
    out[ob + 16] = acc1[reg] * inv;
  }
}

extern "C" void kernel_launch(void* const* d_in, const int* in_sizes, int n_in,
                              void* d_out, int out_size, void* d_ws, size_t ws_size,
                              hipStream_t stream) {
  const float* h   = (const float*)d_in[0];
  const float* adj = (const float*)d_in[1];
  const float* W   = (const float*)d_in[2];
  const float* a   = (const float*)d_in[3];
  float* out = (float*)d_out;

  // ws layout: WhT_hi (2MB) | WhT_lo (2MB) | s1 (64KB) | s2 (64KB)
  unsigned short* wtHi = (unsigned short*)d_ws;
  unsigned short* wtLo = wtHi + (size_t)4 * 64 * 4096;
  float* s1 = (float*)(wtLo + (size_t)4 * 64 * 4096);
  float* s2 = s1 + 16384;

  k_wh  <<<512, 256, 0, stream>>>(h, W, wtHi, wtLo);
  k_s12 <<<64,  256, 0, stream>>>(h, W, a, s1, s2);
  k_main<<<512, 256, 0, stream>>>(adj, wtHi, wtLo, s1, s2, out);
}

// Round 2
// 91.532 us; speedup vs baseline: 1.2355x; 1.2355x over previous
//
#include <hip/hip_runtime.h>
#include <hip/hip_bf16.h>

// GAT layer, B=4, N=4096, F_in=128, F_out=64.
// out_i = sum_j adj_ij * exp(leaky(s2_i+s1_j)) * Wh_j
//         / ( sum_j adj_ij*exp(..) + 1e-9 * sum_j exp(..) )
// softmax max-subtraction cancels exactly; e is O(6) so bare exp2 is safe.
// s1/s2 are stored pre-scaled by log2(e) so P-build is fmax+exp2 only.

typedef __attribute__((ext_vector_type(8))) short bf16x8;
typedef __attribute__((ext_vector_type(4))) float f32x4;

#define LOG2E 1.4426950408889634f

__device__ __forceinline__ unsigned short f2bf(float x) {
  union { float f; unsigned int u; } c; c.f = x;
  unsigned int r = c.u + 0x7fffu + ((c.u >> 16) & 1u);  // RNE
  return (unsigned short)(r >> 16);
}
__device__ __forceinline__ float bf2f(unsigned short s) {
  union { unsigned int u; float f; } c; c.u = ((unsigned int)s) << 16; return c.f;
}

// ---------------- K1: Wh = h @ W (f32); WhT as bf16 hi/lo [b][64][4096];
//                  s1 = Wh a1 * log2e, s2 = Wh a2 * log2e
__global__ __launch_bounds__(256) void k_wh(
    const float* __restrict__ h, const float* __restrict__ W, const float* __restrict__ a,
    unsigned short* __restrict__ wtHi, unsigned short* __restrict__ wtLo,
    float* __restrict__ s1, float* __restrict__ s2) {
  __shared__ float hs[32][130];   // h tile (also reused as WhF)
  const int t = threadIdx.x;
  const int b = blockIdx.x >> 7;
  const int row0 = (blockIdx.x & 127) << 5;   // 32-row tiles

  // stage h tile: 32 rows x 128 f32
  #pragma unroll
  for (int it = 0; it < 4; ++it) {
    int flat = it * 256 + t;
    int r = flat >> 5, q = flat & 31;
    const float4 v = *(const float4*)(h + ((size_t)(b * 4096 + row0 + r)) * 128 + 4 * q);
    hs[r][4*q+0] = v.x; hs[r][4*q+1] = v.y; hs[r][4*q+2] = v.z; hs[r][4*q+3] = v.w;
  }
  __syncthreads();

  const int rg = t >> 4, cg = t & 15;   // thread: rows 2rg..2rg+1, cols 4cg..4cg+3
  float acc[2][4] = {};
  for (int k = 0; k < 128; ++k) {
    float4 wv = *(const float4*)(W + k * 64 + 4 * cg);  // W hot in L1/L2
    #pragma unroll
    for (int i = 0; i < 2; ++i) {
      float hv = hs[2*rg + i][k];
      acc[i][0] = fmaf(hv, wv.x, acc[i][0]);
      acc[i][1] = fmaf(hv, wv.y, acc[i][1]);
      acc[i][2] = fmaf(hv, wv.z, acc[i][2]);
      acc[i][3] = fmaf(hv, wv.w, acc[i][3]);
    }
  }
  __syncthreads();

  float (*WhF)[68] = (float(*)[68])hs;   // 32 x 68 f32, overlays hs
  #pragma unroll
  for (int i = 0; i < 2; ++i)
    #pragma unroll
    for (int j = 0; j < 4; ++j)
      WhF[2*rg + i][4*cg + j] = acc[i][j];
  __syncthreads();

  // s1/s2 from the exact f32 tile (fused former K2), pre-scaled by log2e
  if (t < 32) {
    float x1 = 0.f, x2 = 0.f;
    #pragma unroll 8
    for (int c = 0; c < 64; ++c) {
      float v = WhF[t][c];
      x1 = fmaf(v, a[c], x1);
      x2 = fmaf(v, a[64 + c], x2);
    }
    s1[b * 4096 + row0 + t] = x1 * LOG2E;
    s2[b * 4096 + row0 + t] = x2 * LOG2E;
  }

  // transposed bf16 hi/lo stores (coalesced along N)
  const int col = t >> 2, sub = t & 3;   // thread: one col, 8 rows
  unsigned short hi[8], lo[8];
  #pragma unroll
  for (int r = 0; r < 8; ++r) {
    float v = WhF[8*sub + r][col];
    unsigned short hb = f2bf(v);
    hi[r] = hb;
    lo[r] = f2bf(v - bf2f(hb));   // Wh ~= hi + lo to ~2^-18
  }
  unsigned int uh[4], ul[4];
  #pragma unroll
  for (int r = 0; r < 4; ++r) {
    uh[r] = (unsigned)hi[2*r] | ((unsigned)hi[2*r+1] << 16);
    ul[r] = (unsigned)lo[2*r] | ((unsigned)lo[2*r+1] << 16);
  }
  size_t base = ((size_t)(b * 64 + col)) * 4096 + row0 + 8 * sub;
  *(uint4*)(wtHi + base) = make_uint4(uh[0], uh[1], uh[2], uh[3]);
  *(uint4*)(wtLo + base) = make_uint4(ul[0], ul[1], ul[2], ul[3]);
}

// ---------------- K3: fused  out = P @ (WhHi + WhLo), P built on the fly.
// 32 rows x 64 cols per block, 256 threads (4 waves: 2x2 of 16x32 tiles).
// Depth-2 register prefetch of adj/s1 (HBM), depth-1 of WhT (L2).
// Raw s_barrier + lgkmcnt-only waits: prefetch loads stay in flight.
__global__ __launch_bounds__(256) void k_main(
    const float* __restrict__ adj,
    const unsigned short* __restrict__ wtHi, const unsigned short* __restrict__ wtLo,
    const float* __restrict__ s1, const float* __restrict__ s2,
    float* __restrict__ out) {
  __shared__ unsigned short Pw[32 * 72];    // P tile, rows padded to 72 bf16
  __shared__ unsigned short BhS[64 * 72];   // WhT hi tile [col][k]
  __shared__ unsigned short BlS[64 * 72];   // WhT lo tile
  __shared__ float Zs[32], Ss[32];

  const int t = threadIdx.x;
  const int b = blockIdx.x >> 7;
  const int row0 = (blockIdx.x & 127) << 5;
  const int lane = t & 63, w = t >> 6;
  const int jj = t & 15, prow = t >> 4;       // P-staging role
  const int scol = t >> 2, sq = t & 3;        // WhT-staging role
  const int g = lane >> 4, lr = lane & 15;    // mfma fragment role
  const int rh = w >> 1, ch = w & 1;          // wave -> (row half, col half)

  const float* adjR0 = adj + ((size_t)(b * 4096 + row0) + prow) * 4096 + 4 * jj;
  const float* adjR1 = adjR0 + (size_t)16 * 4096;
  const float s2v0 = s2[b * 4096 + row0 + prow];
  const float s2v1 = s2[b * 4096 + row0 + 16 + prow];
  const unsigned short* gh = wtHi + ((size_t)(b * 64 + scol)) * 4096 + 8 * sq;
  const unsigned short* gl = wtLo + ((size_t)(b * 64 + scol)) * 4096 + 8 * sq;
  const float* s1b = s1 + b * 4096 + 4 * jj;

  float z0 = 0.f, z1 = 0.f, sa0 = 0.f, sa1 = 0.f;
  f32x4 acc0 = {0.f, 0.f, 0.f, 0.f}, acc1 = {0.f, 0.f, 0.f, 0.f};

  // prologue: A(0), A(1) adj/s1 regs; T(0) wt regs
  float4 avA0 = *(const float4*)(adjR0 + 0);
  float4 avA1 = *(const float4*)(adjR1 + 0);
  float4 s1A  = *(const float4*)(s1b + 0);
  float4 avB0 = *(const float4*)(adjR0 + 64);
  float4 avB1 = *(const float4*)(adjR1 + 64);
  float4 s1B  = *(const float4*)(s1b + 64);
  uint4 thC0 = *(const uint4*)(gh + 0);
  uint4 thC1 = *(const uint4*)(gh + 32);
  uint4 tlC0 = *(const uint4*)(gl + 0);
  uint4 tlC1 = *(const uint4*)(gl + 32);

  for (int it = 0; it < 64; ++it) {
    // 1. issue prefetches: A(it+2) (wrapped in-bounds), T(it+1)
    const int kpA = ((it + 2) & 63) << 6;
    const int kpT = ((it + 1) & 63) << 6;
    const float4 p_av0 = *(const float4*)(adjR0 + kpA);
    const float4 p_av1 = *(const float4*)(adjR1 + kpA);
    const float4 p_s1  = *(const float4*)(s1b + kpA);
    const uint4 p_th0 = *(const uint4*)(gh + kpT);
    const uint4 p_th1 = *(const uint4*)(gh + kpT + 32);
    const uint4 p_tl0 = *(const uint4*)(gl + kpT);
    const uint4 p_tl1 = *(const uint4*)(gl + kpT + 32);

    // 2. P build from A(it): rows prow and 16+prow (log2-domain scores)
    {
      float e0 = s2v0 + s1A.x, e1 = s2v0 + s1A.y, e2 = s2v0 + s1A.z, e3 = s2v0 + s1A.w;
      e0 = fmaxf(e0, 0.2f * e0); e1 = fmaxf(e1, 0.2f * e1);
      e2 = fmaxf(e2, 0.2f * e2); e3 = fmaxf(e3, 0.2f * e3);
      float p0 = exp2f(e0), p1 = exp2f(e1), p2 = exp2f(e2), p3 = exp2f(e3);
      float w0 = avA0.x * p0, w1 = avA0.y * p1, w2 = avA0.z * p2, w3 = avA0.w * p3;
      z0 += (p0 + p1) + (p2 + p3);
      sa0 += (w0 + w1) + (w2 + w3);
      ushort4 pk; pk.x = f2bf(w0); pk.y = f2bf(w1); pk.z = f2bf(w2); pk.w = f2bf(w3);
      *(ushort4*)&Pw[prow * 72 + 4 * jj] = pk;
    }
    {
      float e0 = s2v1 + s1A.x, e1 = s2v1 + s1A.y, e2 = s2v1 + s1A.z, e3 = s2v1 + s1A.w;
      e0 = fmaxf(e0, 0.2f * e0); e1 = fmaxf(e1, 0.2f * e1);
      e2 = fmaxf(e2, 0.2f * e2); e3 = fmaxf(e3, 0.2f * e3);
      float p0 = exp2f(e0), p1 = exp2f(e1), p2 = exp2f(e2), p3 = exp2f(e3);
      float w0 = avA1.x * p0, w1 = avA1.y * p1, w2 = avA1.z * p2, w3 = avA1.w * p3;
      z1 += (p0 + p1) + (p2 + p3);
      sa1 += (w0 + w1) + (w2 + w3);
      ushort4 pk; pk.x = f2bf(w0); pk.y = f2bf(w1); pk.z = f2bf(w2); pk.w = f2bf(w3);
      *(ushort4*)&Pw[(16 + prow) * 72 + 4 * jj] = pk;
    }
    // 3. stage WhT hi/lo tiles from T(it)
    *(uint4*)&BhS[scol * 72 + 8 * sq] = thC0;
    *(uint4*)&BhS[scol * 72 + 32 + 8 * sq] = thC1;
    *(uint4*)&BlS[scol * 72 + 8 * sq] = tlC0;
    *(uint4*)&BlS[scol * 72 + 32 + 8 * sq] = tlC1;

    // 4. writes visible, then barrier (NO vmcnt drain — prefetch stays in flight)
    asm volatile("s_waitcnt lgkmcnt(0)" ::: "memory");
    __builtin_amdgcn_sched_barrier(0);
    __builtin_amdgcn_s_barrier();
    __builtin_amdgcn_sched_barrier(0);

    // 5. MFMA: A = P rows [16rh..), B = cols [32ch..)
    #pragma unroll
    for (int kk = 0; kk < 2; ++kk) {
      const bf16x8 af = *(const bf16x8*)&Pw[(16 * rh + lr) * 72 + kk * 32 + 8 * g];
      const int c0 = (32 * ch + lr) * 72 + kk * 32 + 8 * g;
      const bf16x8 bh0 = *(const bf16x8*)&BhS[c0];
      const bf16x8 bl0 = *(const bf16x8*)&BlS[c0];
      const bf16x8 bh1 = *(const bf16x8*)&BhS[c0 + 16 * 72];
      const bf16x8 bl1 = *(const bf16x8*)&BlS[c0 + 16 * 72];
      acc0 = __builtin_amdgcn_mfma_f32_16x16x32_bf16(af, bh0, acc0, 0, 0, 0);
      acc0 = __builtin_amdgcn_mfma_f32_16x16x32_bf16(af, bl0, acc0, 0, 0, 0);
      acc1 = __builtin_amdgcn_mfma_f32_16x16x32_bf16(af, bh1, acc1, 0, 0, 0);
      acc1 = __builtin_amdgcn_mfma_f32_16x16x32_bf16(af, bl1, acc1, 0, 0, 0);
    }

    // 6. all reads consumed; barrier before next iteration's LDS writes
    __builtin_amdgcn_sched_barrier(0);
    __builtin_amdgcn_s_barrier();
    __builtin_amdgcn_sched_barrier(0);

    // 7. shift pipeline registers
    avA0 = avB0; avA1 = avB1; s1A = s1B;
    avB0 = p_av0; avB1 = p_av1; s1B = p_s1;
    thC0 = p_th0; thC1 = p_th1; tlC0 = p_tl0; tlC1 = p_tl1;
  }

  // reduce Z/S across the 16 lanes sharing a row
  #pragma unroll
  for (int m = 1; m < 16; m <<= 1) {
    z0 += __shfl_xor(z0, m);  z1 += __shfl_xor(z1, m);
    sa0 += __shfl_xor(sa0, m); sa1 += __shfl_xor(sa1, m);
  }
  if (jj == 0) {
    Zs[prow] = z0;      Ss[prow] = sa0;
    Zs[16 + prow] = z1; Ss[16 + prow] = sa1;
  }
  __syncthreads();

  // epilogue: scale by 1/(S + eps*Z), write f32 out
  #pragma unroll
  for (int reg = 0; reg < 4; ++reg) {
    int rl = 16 * rh + 4 * g + reg;
    float inv = 1.0f / (Ss[rl] + 1e-9f * Zs[rl]);
    size_t ob = ((size_t)(b * 4096 + row0 + rl)) * 64 + 32 * ch + lr;
    out[ob] = acc0[reg] * inv;
    out[ob + 16] = acc1[reg] * inv;
  }
}

extern "C" void kernel_launch(void* const* d_in, const int* in_sizes, int n_in,
                              void* d_out, int out_size, void* d_ws, size_t ws_size,
                              hipStream_t stream) {
  const float* h   = (const float*)d_in[0];
  const float* adj = (const float*)d_in[1];
  const float* W   = (const float*)d_in[2];
  const float* a   = (const float*)d_in[3];
  float* out = (float*)d_out;

  // ws layout: WhT_hi (2MB) | WhT_lo (2MB) | s1 (64KB) | s2 (64KB)
  unsigned short* wtHi = (unsigned short*)d_ws;
  unsigned short* wtLo = wtHi + (size_t)4 * 64 * 4096;
  float* s1 = (float*)(wtLo + (size_t)4 * 64 * 4096);
  float* s2 = s1 + 16384;

  k_wh  <<<512, 256, 0, stream>>>(h, W, a, wtHi, wtLo, s1, s2);
  k_main<<<512, 256, 0, stream>>>(adj, wtHi, wtLo, s1, s2, out);
}